// Round 9
// baseline (1003.064 us; speedup 1.0000x reference)
//
#include <hip/hip_runtime.h>

// NodeDenoisingADMM: N=20000, FEAT=64, K=4, NNZ=320000, NU=2.0, GAMMA=1.0, J=3
// 14 scan iterations, output = final U (N,FEAT) fp32.
//
// State reduction (GAMMA=1): carried state is v alone.
//   S_t = W_k @ U_t ; Y_t = S_t + v_{t-1} ; Z_t = soft(S_t + Y_t, nu_k d)
//   v_t = Y_t - Z_t ; U_{t+1} = (dm*F - sum_k W_k v_k)/(dm+1), dm = d*mask^2
//
// Node-major CSR: rowid = n*K + k, stored col' = k*N + col.
// wtv runs k-PHASED: phase kk outermost chip-wide, so the live gather set is
// one 2.56MB V_k slice (per-XCD-L2-resident) instead of the 10.2MB whole V.
// Per-node accumulators stay in registers across phases.
// hist uses 8 XCD-privatized count copies (blockIdx&7) to kill atomic-line
// ping-pong across non-coherent XCD L2s.

constexpr int N_    = 20000;
constexpr int FEAT_ = 64;
constexpr int K_    = 4;
constexpr int NNZ_  = 320000;
constexpr int NF    = N_ * FEAT_;     // 1,280,000
constexpr int KN    = K_ * N_;        // 80,000 CSR rows
constexpr int NEDGE = K_ * NNZ_;      // 1,280,000
constexpr int NITER = 14;
constexpr int BLK   = 256;
constexpr int NSB   = (KN + 255) / 256;  // 313 scan blocks
constexpr int NCPY  = 8;                 // hist privatization copies

constexpr int R_SP  = 10;                          // CSR rows/wave, spmm
constexpr int NB_SP = ((KN + R_SP - 1) / R_SP + 3) / 4;   // 2000 blocks
constexpr int R_WT  = 4;                           // nodes/wave, wtv
constexpr int NB_WT = ((N_ + R_WT - 1) / R_WT + 3) / 4;   // 1250 blocks

__constant__ float c_nu[4] = {0.0f, 2.0f, 0.5f, 0.125f};

__device__ __forceinline__ float softf(float x, float t) {
    float a = fabsf(x) - t;
    a = a > 0.0f ? a : 0.0f;
    return copysignf(a, x);
}

__device__ __forceinline__ float bf2f(unsigned short u) {
    union { unsigned int i; float f; } x;
    x.i = ((unsigned int)u) << 16;
    return x.f;
}
__device__ __forceinline__ unsigned short f2bf(float f) {   // RNE
    union { float f; unsigned int i; } x;
    x.f = f;
    unsigned int r = x.i + 0x7FFFu + ((x.i >> 16) & 1u);
    return (unsigned short)(r >> 16);
}

// ---------------- CSR build + precompute ----------------

// dm[n] = d*mask^2 ; F_bf = bf16(F)
__global__ __launch_bounds__(BLK) void precompute_kernel(
    const float* __restrict__ F, const float* __restrict__ d,
    const float* __restrict__ mask, float* __restrict__ dm,
    unsigned short* __restrict__ F_bf) {
    int i = blockIdx.x * BLK + threadIdx.x;       // over NF/4
    if (i >= NF / 4) return;
    float4 f = ((const float4*)F)[i];
    ushort4 o;
    o.x = f2bf(f.x); o.y = f2bf(f.y); o.z = f2bf(f.z); o.w = f2bf(f.w);
    ((ushort4*)F_bf)[i] = o;
    if ((i & (FEAT_ / 4 - 1)) == 0) {
        int n = i / (FEAT_ / 4);
        dm[n] = d[n] * mask[n] * mask[n];
    }
}

// rowid = rows[e]*K + k ; XCD-privatized copies (blockIdx&7)
__global__ __launch_bounds__(BLK) void hist_kernel(
    const int* __restrict__ rows, int* __restrict__ cnt8) {
    int e = blockIdx.x * BLK + threadIdx.x;
    if (e >= NEDGE) return;
    int k = e / NNZ_;
    int copy = blockIdx.x & (NCPY - 1);
    atomicAdd(&cnt8[copy * KN + rows[e] * K_ + k], 1);
}

// block-local exclusive scan over summed copies + block sums
__global__ __launch_bounds__(256) void scan1_kernel(
    const int* __restrict__ cnt8, int* __restrict__ loc,
    int* __restrict__ bsum) {
    int i = blockIdx.x * 256 + threadIdx.x;
    int x = 0;
    if (i < KN) {
        #pragma unroll
        for (int c = 0; c < NCPY; ++c) x += cnt8[c * KN + i];
    }
    int lane = threadIdx.x & 63, wid = threadIdx.x >> 6;
    int v = x;
    #pragma unroll
    for (int off = 1; off < 64; off <<= 1) {
        int t = __shfl_up(v, off, 64);
        if (lane >= off) v += t;
    }
    __shared__ int ws[4];
    if (lane == 63) ws[wid] = v;
    __syncthreads();
    int add = 0;
    for (int u = 0; u < wid; ++u) add += ws[u];
    v += add;
    if (i < KN) loc[i] = v - x;
    if (threadIdx.x == 255) bsum[blockIdx.x] = v;
}

__global__ __launch_bounds__(512) void scan2_kernel(int* __restrict__ bsum) {
    int tid = threadIdx.x;
    int x = (tid < NSB) ? bsum[tid] : 0;
    int lane = tid & 63, wid = tid >> 6;
    int v = x;
    #pragma unroll
    for (int off = 1; off < 64; off <<= 1) {
        int t = __shfl_up(v, off, 64);
        if (lane >= off) v += t;
    }
    __shared__ int ws[8];
    if (lane == 63) ws[wid] = v;
    __syncthreads();
    int add = 0;
    for (int u = 0; u < wid; ++u) add += ws[u];
    v += add;
    if (tid < NSB) bsum[tid] = v - x;
}

__global__ __launch_bounds__(256) void scan3_kernel(
    const int* __restrict__ loc, const int* __restrict__ bsum,
    int* __restrict__ offs, int* __restrict__ cursor) {
    int i = blockIdx.x * 256 + threadIdx.x;
    if (i < KN) {
        int v = loc[i] + bsum[blockIdx.x];
        offs[i] = v;
        cursor[i] = v;
    }
    if (i == 0) offs[KN] = NEDGE;
}

// direct scatter: one 8-B random write per edge; stores col' = k*N + col
__global__ __launch_bounds__(BLK) void scatter_kernel(
    const int* __restrict__ rows, const int* __restrict__ cols,
    const float* __restrict__ vals, int* __restrict__ cursor,
    int2* __restrict__ cmeta) {
    int e = blockIdx.x * BLK + threadIdx.x;
    if (e >= NEDGE) return;
    int k = e / NNZ_;
    int pos = atomicAdd(&cursor[rows[e] * K_ + k], 1);
    cmeta[pos] = make_int2(k * N_ + cols[e], __float_as_int(vals[e]));
}

// ---------------- iteration kernels ----------------

// Accumulate edges [beg,end) into acc. bf16 gather (ushort4, 128B/row-read),
// fp32 FMA. Meta loaded lane-parallel per 64-edge chunk, broadcast via __shfl.
// Gathers issued in batches of BATCH for MLP. Pad column = padc (in-bounds).
template <int BATCH>
__device__ __forceinline__ void row_accum_bf(
    const int2* __restrict__ cmeta, const ushort4* __restrict__ Xb,
    int beg, int end, int lane, int sub, int q, int padc, float4& acc) {
    for (int ebase = beg; ebase < end; ebase += 64) {
        int n = end - ebase;             // wave-uniform
        if (n > 64) n = 64;
        int   c_l = padc;
        float v_l = 0.0f;
        if (lane < n) {
            int2 m = cmeta[ebase + lane];
            c_l = m.x;
            v_l = __int_as_float(m.y);
        }
        int iters = (n + 3) >> 2;
        int itersPad = (iters + BATCH - 1) & ~(BATCH - 1);  // <= 16
        for (int it0 = 0; it0 < itersPad; it0 += BATCH) {
            float   vv[BATCH];
            ushort4 xx[BATCH];
            #pragma unroll
            for (int u = 0; u < BATCH; ++u) {
                int j = 4 * (it0 + u) + sub;      // < 64
                int   c = __shfl(c_l, j, 64);
                vv[u]   = __shfl(v_l, j, 64);
                xx[u]   = Xb[c * (FEAT_ / 4) + q];
            }
            #pragma unroll
            for (int u = 0; u < BATCH; ++u) {
                acc.x += vv[u] * bf2f(xx[u].x);
                acc.y += vv[u] * bf2f(xx[u].y);
                acc.z += vv[u] * bf2f(xx[u].z);
                acc.w += vv[u] * bf2f(xx[u].w);
            }
        }
    }
}

__device__ __forceinline__ void butterfly4(float4& a) {
    #pragma unroll
    for (int m = 16; m <= 32; m <<= 1) {
        a.x += __shfl_xor(a.x, m, 64);
        a.y += __shfl_xor(a.y, m, 64);
        a.z += __shfl_xor(a.z, m, 64);
        a.w += __shfl_xor(a.w, m, 64);
    }
}

// wave per R_SP contiguous CSR rows (rowid = n*K+k); acc = (W_k @ X)[n];
// fused v-update into bf16 V_bf (layout [k][n]). FIRST: Y=0, X=F_bf.
template <bool FIRST>
__global__ __launch_bounds__(BLK) void spmm_fused_kernel(
    const int* __restrict__ offs, const int2* __restrict__ cmeta,
    const unsigned short* __restrict__ Xb,
    const float* __restrict__ d, unsigned short* __restrict__ V_bf) {
    int wave = (blockIdx.x * BLK + threadIdx.x) >> 6;
    int lane = threadIdx.x & 63;
    int sub  = lane >> 4, q = lane & 15;
    int base = wave * R_SP;
    if (base >= KN) return;
    int off_l = 0;
    if (lane <= R_SP) {
        int i = base + lane;
        if (i > KN) i = KN;
        off_l = offs[i];
    }
    const ushort4* X4 = (const ushort4*)Xb;
    ushort4* V4 = (ushort4*)V_bf;
    for (int r = 0; r < R_SP; ++r) {
        int w = base + r;                // rowid = n*K + k
        if (w >= KN) break;
        int k = w & (K_ - 1);
        int n = w >> 2;
        int beg = __shfl(off_l, r, 64);
        int end = __shfl(off_l, r + 1, 64);
        // col' = k*N + col; recover shared-X indexing via base adjust (free)
        const ushort4* X4m = X4 - (size_t)k * N_ * (FEAT_ / 4);
        float4 acc = {0.f, 0.f, 0.f, 0.f};
        row_accum_bf<4>(cmeta, X4m, beg, end, lane, sub, q, k * N_, acc);
        butterfly4(acc);                 // all lanes hold row sums
        if (sub == 0) {
            int idx4 = (k * N_ + n) * (FEAT_ / 4) + q;
            float thr = c_nu[k] * d[n];
            float4 y;
            if (FIRST) {
                y = make_float4(0.f, 0.f, 0.f, 0.f);
            } else {
                ushort4 vp = V4[idx4];   // v_{t-1}
                y.x = acc.x + bf2f(vp.x); y.y = acc.y + bf2f(vp.y);
                y.z = acc.z + bf2f(vp.z); y.w = acc.w + bf2f(vp.w);
            }
            ushort4 o;
            o.x = f2bf(y.x - softf(acc.x + y.x, thr));
            o.y = f2bf(y.y - softf(acc.y + y.y, thr));
            o.z = f2bf(y.z - softf(acc.z + y.z, thr));
            o.w = f2bf(y.w - softf(acc.w + y.w, thr));
            V4[idx4] = o;                // v_t
        }
    }
}

// wave per R_WT nodes, K-PHASED: phase kk outermost so the whole chip gathers
// from one 2.56MB V_k slice at a time (per-XCD-L2-resident). Per-node
// accumulators persist in registers across phases.
// U = (dm*F - acc)/(dm+1), stored fp32 (d_out) + bf16 (gather copy).
__global__ __launch_bounds__(BLK) void wtv_u_kernel(
    const int* __restrict__ offs, const int2* __restrict__ cmeta,
    const unsigned short* __restrict__ V_bf,
    const float* __restrict__ F, const float* __restrict__ dm,
    float* __restrict__ U, unsigned short* __restrict__ U_bf) {
    int wave = (blockIdx.x * BLK + threadIdx.x) >> 6;
    int lane = threadIdx.x & 63;
    int sub  = lane >> 4, q = lane & 15;
    int base = wave * R_WT;
    if (base >= N_) return;
    int off_l = 0;
    if (lane <= K_ * R_WT) {             // 17 offsets
        int i = K_ * base + lane;
        if (i > KN) i = KN;
        off_l = offs[i];
    }
    const ushort4* V4 = (const ushort4*)V_bf;
    float4 acc[R_WT];
    #pragma unroll
    for (int r = 0; r < R_WT; ++r) acc[r] = make_float4(0.f, 0.f, 0.f, 0.f);
    for (int kk = 0; kk < K_; ++kk) {    // phase loop (chip-wide coherent)
        #pragma unroll
        for (int r = 0; r < R_WT; ++r) {
            int n = base + r;
            if (n >= N_) break;
            int beg = __shfl(off_l, K_ * r + kk, 64);
            int end = __shfl(off_l, K_ * r + kk + 1, 64);
            row_accum_bf<4>(cmeta, V4, beg, end, lane, sub, q, 0, acc[r]);
        }
    }
    #pragma unroll
    for (int r = 0; r < R_WT; ++r) {
        int n = base + r;
        if (n >= N_) break;
        butterfly4(acc[r]);
        if (sub == 0) {
            int idx4 = n * (FEAT_ / 4) + q;
            float dmv = dm[n];
            float r2 = 1.0f / (dmv + 1.0f);
            float4 f = ((const float4*)F)[idx4];
            float4 o;
            o.x = (dmv * f.x - acc[r].x) * r2; o.y = (dmv * f.y - acc[r].y) * r2;
            o.z = (dmv * f.z - acc[r].z) * r2; o.w = (dmv * f.w - acc[r].w) * r2;
            ((float4*)U)[idx4] = o;
            ushort4 ob;
            ob.x = f2bf(o.x); ob.y = f2bf(o.y);
            ob.z = f2bf(o.z); ob.w = f2bf(o.w);
            ((ushort4*)U_bf)[idx4] = ob;
        }
    }
}

extern "C" void kernel_launch(void* const* d_in, const int* in_sizes, int n_in,
                              void* d_out, int out_size, void* d_ws, size_t ws_size,
                              hipStream_t stream) {
    const float* F      = (const float*)d_in[0];
    const int*   w_rows = (const int*)d_in[1];
    const int*   w_cols = (const int*)d_in[2];
    const float* w_vals = (const float*)d_in[3];
    const float* d      = (const float*)d_in[4];
    const float* mask   = (const float*)d_in[5];
    float* U = (float*)d_out;

    // workspace layout (~32 MB); cmeta first for 8/16-B alignment
    int2* cmeta          = (int2*)d_ws;                       // NEDGE int2
    unsigned short* V_bf = (unsigned short*)(cmeta + NEDGE);  // KN*FEAT us
    unsigned short* U_bf = V_bf + (size_t)KN * FEAT_;         // NF us
    unsigned short* F_bf = U_bf + NF;                         // NF us
    float* dm     = (float*)(F_bf + NF);                      // N
    int*   cnt8   = (int*)(dm + N_);                          // NCPY*KN
    int*   loc    = cnt8 + NCPY * KN;                         // KN
    int*   bsum   = loc + KN;                                 // pad 512
    int*   offs   = bsum + 512;                               // KN+1
    int*   cursor = offs + KN + 1;                            // KN

    const int gEdge = NEDGE / BLK;                // 5000
    const int gNF4  = (NF / 4) / BLK;             // 1250

    // ---- CSR build + precompute ----
    hipMemsetAsync(cnt8, 0, (size_t)NCPY * KN * 4, stream);
    precompute_kernel<<<gNF4, BLK, 0, stream>>>(F, d, mask, dm, F_bf);
    hist_kernel<<<gEdge, BLK, 0, stream>>>(w_rows, cnt8);
    scan1_kernel<<<NSB, 256, 0, stream>>>(cnt8, loc, bsum);
    scan2_kernel<<<1, 512, 0, stream>>>(bsum);
    scan3_kernel<<<NSB, 256, 0, stream>>>(loc, bsum, offs, cursor);
    scatter_kernel<<<gEdge, BLK, 0, stream>>>(w_rows, w_cols, w_vals,
                                              cursor, cmeta);

    // ---- iterations ----
    spmm_fused_kernel<true><<<NB_SP, BLK, 0, stream>>>(offs, cmeta, F_bf, d, V_bf);
    for (int it = 0; it < NITER; ++it) {
        wtv_u_kernel<<<NB_WT, BLK, 0, stream>>>(offs, cmeta, V_bf,
                                                F, dm, U, U_bf);
        if (it < NITER - 1)
            spmm_fused_kernel<false><<<NB_SP, BLK, 0, stream>>>(offs, cmeta,
                                                                U_bf, d, V_bf);
    }
}

// Round 10
// 958.775 us; speedup vs baseline: 1.0462x; 1.0462x over previous
//
#include <hip/hip_runtime.h>

// NodeDenoisingADMM: N=20000, FEAT=64, K=4, NNZ=320000, NU=2.0, GAMMA=1.0, J=3
// 14 scan iterations, output = final U (N,FEAT) fp32.
//
// State reduction (GAMMA=1): carried state is v alone.
//   S_t = W_k @ U_t ; Y_t = S_t + v_{t-1} ; Z_t = soft(S_t + Y_t, nu_k d)
//   v_t = Y_t - Z_t ; U_{t+1} = (dm*F - sum_k W_k v_k)/(dm+1), dm = d*mask^2
//
// Node-major CSR: rowid = n*K + k. Edge meta packed in 4 B:
//   [31] sign | [30:26] exp5 (bias 96, 0 => value 0) | [25:17] mant9 (RNE)
//   | [16:15] k | [14:0] col       (rel err 2^-11 < bf16 operand err)
// wtv: node n's edges over all k contiguous -> one flat segment.
// spmm: per-(n,k) row; shared-X recovered via -k*N base adjust.
// Gather operands (U,V,F) are bf16 side copies; gathers batched (4 spmm /
// 8 wtv) for memory-level parallelism. hist uses 8 privatized count copies.

constexpr int N_    = 20000;
constexpr int FEAT_ = 64;
constexpr int K_    = 4;
constexpr int NNZ_  = 320000;
constexpr int NF    = N_ * FEAT_;     // 1,280,000
constexpr int KN    = K_ * N_;        // 80,000 CSR rows
constexpr int NEDGE = K_ * NNZ_;      // 1,280,000
constexpr int NITER = 14;
constexpr int BLK   = 256;
constexpr int NSB   = (KN + 255) / 256;  // 313 scan blocks
constexpr int NCPY  = 8;                 // hist privatization copies

constexpr int R_SP  = 10;                          // CSR rows/wave, spmm
constexpr int NB_SP = ((KN + R_SP - 1) / R_SP + 3) / 4;   // 2000 blocks
constexpr int R_WT  = 4;                           // nodes/wave, wtv
constexpr int NB_WT = ((N_ + R_WT - 1) / R_WT + 3) / 4;   // 1250 blocks

__constant__ float c_nu[4] = {0.0f, 2.0f, 0.5f, 0.125f};

__device__ __forceinline__ float softf(float x, float t) {
    float a = fabsf(x) - t;
    a = a > 0.0f ? a : 0.0f;
    return copysignf(a, x);
}

__device__ __forceinline__ float bf2f(unsigned short u) {
    union { unsigned int i; float f; } x;
    x.i = ((unsigned int)u) << 16;
    return x.f;
}
__device__ __forceinline__ unsigned short f2bf(float f) {   // RNE
    union { float f; unsigned int i; } x;
    x.f = f;
    unsigned int r = x.i + 0x7FFFu + ((x.i >> 16) & 1u);
    return (unsigned short)(r >> 16);
}

// ---------------- CSR build + precompute ----------------

// dm[n] = d*mask^2 ; F_bf = bf16(F)
__global__ __launch_bounds__(BLK) void precompute_kernel(
    const float* __restrict__ F, const float* __restrict__ d,
    const float* __restrict__ mask, float* __restrict__ dm,
    unsigned short* __restrict__ F_bf) {
    int i = blockIdx.x * BLK + threadIdx.x;       // over NF/4
    if (i >= NF / 4) return;
    float4 f = ((const float4*)F)[i];
    ushort4 o;
    o.x = f2bf(f.x); o.y = f2bf(f.y); o.z = f2bf(f.z); o.w = f2bf(f.w);
    ((ushort4*)F_bf)[i] = o;
    if ((i & (FEAT_ / 4 - 1)) == 0) {
        int n = i / (FEAT_ / 4);
        dm[n] = d[n] * mask[n] * mask[n];
    }
}

// rowid = rows[e]*K + k ; privatized copies (blockIdx&7)
__global__ __launch_bounds__(BLK) void hist_kernel(
    const int* __restrict__ rows, int* __restrict__ cnt8) {
    int e = blockIdx.x * BLK + threadIdx.x;
    if (e >= NEDGE) return;
    int k = e / NNZ_;
    int copy = blockIdx.x & (NCPY - 1);
    atomicAdd(&cnt8[copy * KN + rows[e] * K_ + k], 1);
}

// block-local exclusive scan over summed copies + block sums
__global__ __launch_bounds__(256) void scan1_kernel(
    const int* __restrict__ cnt8, int* __restrict__ loc,
    int* __restrict__ bsum) {
    int i = blockIdx.x * 256 + threadIdx.x;
    int x = 0;
    if (i < KN) {
        #pragma unroll
        for (int c = 0; c < NCPY; ++c) x += cnt8[c * KN + i];
    }
    int lane = threadIdx.x & 63, wid = threadIdx.x >> 6;
    int v = x;
    #pragma unroll
    for (int off = 1; off < 64; off <<= 1) {
        int t = __shfl_up(v, off, 64);
        if (lane >= off) v += t;
    }
    __shared__ int ws[4];
    if (lane == 63) ws[wid] = v;
    __syncthreads();
    int add = 0;
    for (int u = 0; u < wid; ++u) add += ws[u];
    v += add;
    if (i < KN) loc[i] = v - x;
    if (threadIdx.x == 255) bsum[blockIdx.x] = v;
}

__global__ __launch_bounds__(512) void scan2_kernel(int* __restrict__ bsum) {
    int tid = threadIdx.x;
    int x = (tid < NSB) ? bsum[tid] : 0;
    int lane = tid & 63, wid = tid >> 6;
    int v = x;
    #pragma unroll
    for (int off = 1; off < 64; off <<= 1) {
        int t = __shfl_up(v, off, 64);
        if (lane >= off) v += t;
    }
    __shared__ int ws[8];
    if (lane == 63) ws[wid] = v;
    __syncthreads();
    int add = 0;
    for (int u = 0; u < wid; ++u) add += ws[u];
    v += add;
    if (tid < NSB) bsum[tid] = v - x;
}

__global__ __launch_bounds__(256) void scan3_kernel(
    const int* __restrict__ loc, const int* __restrict__ bsum,
    int* __restrict__ offs, int* __restrict__ cursor) {
    int i = blockIdx.x * 256 + threadIdx.x;
    if (i < KN) {
        int v = loc[i] + bsum[blockIdx.x];
        offs[i] = v;
        cursor[i] = v;
    }
    if (i == 0) offs[KN] = NEDGE;
}

// direct scatter: ONE 4-B random write per edge (packed meta)
__global__ __launch_bounds__(BLK) void scatter_kernel(
    const int* __restrict__ rows, const int* __restrict__ cols,
    const float* __restrict__ vals, int* __restrict__ cursor,
    unsigned int* __restrict__ cmeta) {
    int e = blockIdx.x * BLK + threadIdx.x;
    if (e >= NEDGE) return;
    int k = e / NNZ_;
    unsigned int b  = __float_as_uint(vals[e]);
    unsigned int rb = b + 0x1FFFu + ((b >> 14) & 1u);   // RNE to 9 mant bits
    int exp8 = (int)((rb >> 23) & 0xFF);
    unsigned int pk = 0u;
    if (exp8 > 96)                                       // else flush to 0
        pk = (b & 0x80000000u) | ((unsigned int)(exp8 - 96) << 26) |
             (((rb >> 14) & 0x1FFu) << 17);
    pk |= ((unsigned int)k << 15) | (unsigned int)cols[e];
    int pos = atomicAdd(&cursor[rows[e] * K_ + k], 1);
    cmeta[pos] = pk;
}

// ---------------- iteration kernels ----------------

// Accumulate edges [beg,end) into acc. bf16 gather (ushort4, 128B/row-read),
// fp32 FMA. Packed meta loaded lane-parallel per 64-edge chunk, decoded once
// per lane, broadcast via __shfl. Gathers batched (BATCH) for MLP.
// Pad column index = padc (in-bounds for the adjusted base).
template <int BATCH>
__device__ __forceinline__ void row_accum_bf(
    const unsigned int* __restrict__ cmeta, const ushort4* __restrict__ Xb,
    int beg, int end, int lane, int sub, int q, int padc, float4& acc) {
    for (int ebase = beg; ebase < end; ebase += 64) {
        int n = end - ebase;             // wave-uniform
        if (n > 64) n = 64;
        int   c_l = padc;
        float v_l = 0.0f;
        if (lane < n) {
            unsigned int p = cmeta[ebase + lane];
            c_l = (int)((p >> 15) & 3u) * N_ + (int)(p & 0x7FFFu);
            unsigned int e5 = (p >> 26) & 0x1Fu;
            unsigned int bits = (p & 0x80000000u) | ((e5 + 96u) << 23) |
                                (((p >> 17) & 0x1FFu) << 14);
            v_l = (e5 == 0u) ? 0.0f : __uint_as_float(bits);
        }
        int iters = (n + 3) >> 2;
        int itersPad = (iters + BATCH - 1) & ~(BATCH - 1);  // <= 16
        for (int it0 = 0; it0 < itersPad; it0 += BATCH) {
            float   vv[BATCH];
            ushort4 xx[BATCH];
            #pragma unroll
            for (int u = 0; u < BATCH; ++u) {
                int j = 4 * (it0 + u) + sub;      // < 64
                int   c = __shfl(c_l, j, 64);
                vv[u]   = __shfl(v_l, j, 64);
                xx[u]   = Xb[c * (FEAT_ / 4) + q];
            }
            #pragma unroll
            for (int u = 0; u < BATCH; ++u) {
                acc.x += vv[u] * bf2f(xx[u].x);
                acc.y += vv[u] * bf2f(xx[u].y);
                acc.z += vv[u] * bf2f(xx[u].z);
                acc.w += vv[u] * bf2f(xx[u].w);
            }
        }
    }
}

__device__ __forceinline__ void butterfly4(float4& a) {
    #pragma unroll
    for (int m = 16; m <= 32; m <<= 1) {
        a.x += __shfl_xor(a.x, m, 64);
        a.y += __shfl_xor(a.y, m, 64);
        a.z += __shfl_xor(a.z, m, 64);
        a.w += __shfl_xor(a.w, m, 64);
    }
}

// wave per R_SP contiguous CSR rows (rowid = n*K+k); acc = (W_k @ X)[n];
// fused v-update into bf16 V_bf (layout [k][n]). FIRST: Y=0, X=F_bf.
template <bool FIRST>
__global__ __launch_bounds__(BLK) void spmm_fused_kernel(
    const int* __restrict__ offs, const unsigned int* __restrict__ cmeta,
    const unsigned short* __restrict__ Xb,
    const float* __restrict__ d, unsigned short* __restrict__ V_bf) {
    int wave = (blockIdx.x * BLK + threadIdx.x) >> 6;
    int lane = threadIdx.x & 63;
    int sub  = lane >> 4, q = lane & 15;
    int base = wave * R_SP;
    if (base >= KN) return;
    int off_l = 0;
    if (lane <= R_SP) {
        int i = base + lane;
        if (i > KN) i = KN;
        off_l = offs[i];
    }
    const ushort4* X4 = (const ushort4*)Xb;
    ushort4* V4 = (ushort4*)V_bf;
    for (int r = 0; r < R_SP; ++r) {
        int w = base + r;                // rowid = n*K + k
        if (w >= KN) break;
        int k = w & (K_ - 1);
        int n = w >> 2;
        int beg = __shfl(off_l, r, 64);
        int end = __shfl(off_l, r + 1, 64);
        // decoded col' = k*N + col; recover shared-X indexing by base adjust
        const ushort4* X4m = X4 - (size_t)k * N_ * (FEAT_ / 4);
        float4 acc = {0.f, 0.f, 0.f, 0.f};
        row_accum_bf<4>(cmeta, X4m, beg, end, lane, sub, q, k * N_, acc);
        butterfly4(acc);                 // all lanes hold row sums
        if (sub == 0) {
            int idx4 = (k * N_ + n) * (FEAT_ / 4) + q;
            float thr = c_nu[k] * d[n];
            float4 y;
            if (FIRST) {
                y = make_float4(0.f, 0.f, 0.f, 0.f);
            } else {
                ushort4 vp = V4[idx4];   // v_{t-1}
                y.x = acc.x + bf2f(vp.x); y.y = acc.y + bf2f(vp.y);
                y.z = acc.z + bf2f(vp.z); y.w = acc.w + bf2f(vp.w);
            }
            ushort4 o;
            o.x = f2bf(y.x - softf(acc.x + y.x, thr));
            o.y = f2bf(y.y - softf(acc.y + y.y, thr));
            o.z = f2bf(y.z - softf(acc.z + y.z, thr));
            o.w = f2bf(y.w - softf(acc.w + y.w, thr));
            V4[idx4] = o;                // v_t
        }
    }
}

// wave per R_WT nodes: node n's edges over ALL k are one flat contiguous
// segment [offs[4n], offs[4n+4]) gathering V_bf[col'] directly.
// U = (dm*F - acc)/(dm+1), stored fp32 (d_out) + bf16 (gather copy).
__global__ __launch_bounds__(BLK) void wtv_u_kernel(
    const int* __restrict__ offs, const unsigned int* __restrict__ cmeta,
    const unsigned short* __restrict__ V_bf,
    const float* __restrict__ F, const float* __restrict__ dm,
    float* __restrict__ U, unsigned short* __restrict__ U_bf) {
    int wave = (blockIdx.x * BLK + threadIdx.x) >> 6;
    int lane = threadIdx.x & 63;
    int sub  = lane >> 4, q = lane & 15;
    int base = wave * R_WT;
    if (base >= N_) return;
    int off_l = 0;
    if (lane <= K_ * R_WT) {             // 17 offsets
        int i = K_ * base + lane;
        if (i > KN) i = KN;
        off_l = offs[i];
    }
    const ushort4* V4 = (const ushort4*)V_bf;
    for (int r = 0; r < R_WT; ++r) {
        int n = base + r;
        if (n >= N_) break;
        int beg = __shfl(off_l, K_ * r, 64);
        int end = __shfl(off_l, K_ * r + K_, 64);
        float4 acc = {0.f, 0.f, 0.f, 0.f};
        row_accum_bf<8>(cmeta, V4, beg, end, lane, sub, q, 0, acc);
        butterfly4(acc);
        if (sub == 0) {
            int idx4 = n * (FEAT_ / 4) + q;
            float dmv = dm[n];
            float r2 = 1.0f / (dmv + 1.0f);
            float4 f = ((const float4*)F)[idx4];
            float4 o;
            o.x = (dmv * f.x - acc.x) * r2; o.y = (dmv * f.y - acc.y) * r2;
            o.z = (dmv * f.z - acc.z) * r2; o.w = (dmv * f.w - acc.w) * r2;
            ((float4*)U)[idx4] = o;
            ushort4 ob;
            ob.x = f2bf(o.x); ob.y = f2bf(o.y);
            ob.z = f2bf(o.z); ob.w = f2bf(o.w);
            ((ushort4*)U_bf)[idx4] = ob;
        }
    }
}

extern "C" void kernel_launch(void* const* d_in, const int* in_sizes, int n_in,
                              void* d_out, int out_size, void* d_ws, size_t ws_size,
                              hipStream_t stream) {
    const float* F      = (const float*)d_in[0];
    const int*   w_rows = (const int*)d_in[1];
    const int*   w_cols = (const int*)d_in[2];
    const float* w_vals = (const float*)d_in[3];
    const float* d      = (const float*)d_in[4];
    const float* mask   = (const float*)d_in[5];
    float* U = (float*)d_out;

    // workspace layout (~29 MB)
    unsigned int* cmeta  = (unsigned int*)d_ws;               // NEDGE u32
    unsigned short* V_bf = (unsigned short*)(cmeta + NEDGE);  // KN*FEAT us
    unsigned short* U_bf = V_bf + (size_t)KN * FEAT_;         // NF us
    unsigned short* F_bf = U_bf + NF;                         // NF us
    float* dm     = (float*)(F_bf + NF);                      // N
    int*   cnt8   = (int*)(dm + N_);                          // NCPY*KN
    int*   loc    = cnt8 + NCPY * KN;                         // KN
    int*   bsum   = loc + KN;                                 // pad 512
    int*   offs   = bsum + 512;                               // KN+1
    int*   cursor = offs + KN + 1;                            // KN

    const int gEdge = NEDGE / BLK;                // 5000
    const int gNF4  = (NF / 4) / BLK;             // 1250

    // ---- CSR build + precompute ----
    hipMemsetAsync(cnt8, 0, (size_t)NCPY * KN * 4, stream);
    precompute_kernel<<<gNF4, BLK, 0, stream>>>(F, d, mask, dm, F_bf);
    hist_kernel<<<gEdge, BLK, 0, stream>>>(w_rows, cnt8);
    scan1_kernel<<<NSB, 256, 0, stream>>>(cnt8, loc, bsum);
    scan2_kernel<<<1, 512, 0, stream>>>(bsum);
    scan3_kernel<<<NSB, 256, 0, stream>>>(loc, bsum, offs, cursor);
    scatter_kernel<<<gEdge, BLK, 0, stream>>>(w_rows, w_cols, w_vals,
                                              cursor, cmeta);

    // ---- iterations ----
    spmm_fused_kernel<true><<<NB_SP, BLK, 0, stream>>>(offs, cmeta, F_bf, d, V_bf);
    for (int it = 0; it < NITER; ++it) {
        wtv_u_kernel<<<NB_WT, BLK, 0, stream>>>(offs, cmeta, V_bf,
                                                F, dm, U, U_bf);
        if (it < NITER - 1)
            spmm_fused_kernel<false><<<NB_SP, BLK, 0, stream>>>(offs, cmeta,
                                                                U_bf, d, V_bf);
    }
}

// Round 11
// 929.888 us; speedup vs baseline: 1.0787x; 1.0311x over previous
//
#include <hip/hip_runtime.h>

// NodeDenoisingADMM: N=20000, FEAT=64, K=4, NNZ=320000, NU=2.0, GAMMA=1.0, J=3
// 14 scan iterations, output = final U (N,FEAT) fp32.
//
// State reduction (GAMMA=1): carried state is v alone.
//   S_t = W_k @ U_t ; Y_t = S_t + v_{t-1} ; Z_t = soft(S_t + Y_t, nu_k d)
//   v_t = Y_t - Z_t ; U_{t+1} = (dm*F - sum_k W_k v_k)/(dm+1), dm = d*mask^2
//
// Node-major CSR: rowid = n*K + k. Edge meta packed in 4 B:
//   [31] sign | [30:26] exp5 (bias 96, 0 => value 0) | [25:17] mant9 (RNE)
//   | [16:15] k | [14:0] col       (rel err 2^-11 < bf16 operand err)
// Scatter is XCD-FILTERED: rows bucketed into 8 groups (row/2500); block
// processes only edges of bucket blockIdx%8 (round-robin block->XCD mapping
// keeps each bucket's cursor lines + cmeta region in ONE XCD's L2 -> no
// cross-XCD line ping-pong; R10 showed WRITE_SIZE is bounce-count-bound).
// wtv: node n's edges over all k contiguous -> one flat segment.
// spmm: per-(n,k) row; shared-X recovered via -k*N base adjust.
// Gather operands (U,V,F) are bf16 side copies; gathers batched (4 spmm /
// 8 wtv) for memory-level parallelism. hist uses 8 privatized count copies.

constexpr int N_    = 20000;
constexpr int FEAT_ = 64;
constexpr int K_    = 4;
constexpr int NNZ_  = 320000;
constexpr int NF    = N_ * FEAT_;     // 1,280,000
constexpr int KN    = K_ * N_;        // 80,000 CSR rows
constexpr int NEDGE = K_ * NNZ_;      // 1,280,000
constexpr int NITER = 14;
constexpr int BLK   = 256;
constexpr int NSB   = (KN + 255) / 256;  // 313 scan blocks
constexpr int NCPY  = 8;                 // hist privatization copies
constexpr int NXCD  = 8;
constexpr int EPV   = 2048;              // edges per virtual scatter block
constexpr int NVB   = NEDGE / EPV;       // 625 virtual blocks

constexpr int R_SP  = 10;                          // CSR rows/wave, spmm
constexpr int NB_SP = ((KN + R_SP - 1) / R_SP + 3) / 4;   // 2000 blocks
constexpr int R_WT  = 4;                           // nodes/wave, wtv
constexpr int NB_WT = ((N_ + R_WT - 1) / R_WT + 3) / 4;   // 1250 blocks

__constant__ float c_nu[4] = {0.0f, 2.0f, 0.5f, 0.125f};

__device__ __forceinline__ float softf(float x, float t) {
    float a = fabsf(x) - t;
    a = a > 0.0f ? a : 0.0f;
    return copysignf(a, x);
}

__device__ __forceinline__ float bf2f(unsigned short u) {
    union { unsigned int i; float f; } x;
    x.i = ((unsigned int)u) << 16;
    return x.f;
}
__device__ __forceinline__ unsigned short f2bf(float f) {   // RNE
    union { float f; unsigned int i; } x;
    x.f = f;
    unsigned int r = x.i + 0x7FFFu + ((x.i >> 16) & 1u);
    return (unsigned short)(r >> 16);
}

// ---------------- CSR build + precompute ----------------

// dm[n] = d*mask^2 ; F_bf = bf16(F)
__global__ __launch_bounds__(BLK) void precompute_kernel(
    const float* __restrict__ F, const float* __restrict__ d,
    const float* __restrict__ mask, float* __restrict__ dm,
    unsigned short* __restrict__ F_bf) {
    int i = blockIdx.x * BLK + threadIdx.x;       // over NF/4
    if (i >= NF / 4) return;
    float4 f = ((const float4*)F)[i];
    ushort4 o;
    o.x = f2bf(f.x); o.y = f2bf(f.y); o.z = f2bf(f.z); o.w = f2bf(f.w);
    ((ushort4*)F_bf)[i] = o;
    if ((i & (FEAT_ / 4 - 1)) == 0) {
        int n = i / (FEAT_ / 4);
        dm[n] = d[n] * mask[n] * mask[n];
    }
}

// rowid = rows[e]*K + k ; privatized copies (blockIdx&7)
__global__ __launch_bounds__(BLK) void hist_kernel(
    const int* __restrict__ rows, int* __restrict__ cnt8) {
    int e = blockIdx.x * BLK + threadIdx.x;
    if (e >= NEDGE) return;
    int k = e / NNZ_;
    int copy = blockIdx.x & (NCPY - 1);
    atomicAdd(&cnt8[copy * KN + rows[e] * K_ + k], 1);
}

// block-local exclusive scan over summed copies + block sums
__global__ __launch_bounds__(256) void scan1_kernel(
    const int* __restrict__ cnt8, int* __restrict__ loc,
    int* __restrict__ bsum) {
    int i = blockIdx.x * 256 + threadIdx.x;
    int x = 0;
    if (i < KN) {
        #pragma unroll
        for (int c = 0; c < NCPY; ++c) x += cnt8[c * KN + i];
    }
    int lane = threadIdx.x & 63, wid = threadIdx.x >> 6;
    int v = x;
    #pragma unroll
    for (int off = 1; off < 64; off <<= 1) {
        int t = __shfl_up(v, off, 64);
        if (lane >= off) v += t;
    }
    __shared__ int ws[4];
    if (lane == 63) ws[wid] = v;
    __syncthreads();
    int add = 0;
    for (int u = 0; u < wid; ++u) add += ws[u];
    v += add;
    if (i < KN) loc[i] = v - x;
    if (threadIdx.x == 255) bsum[blockIdx.x] = v;
}

__global__ __launch_bounds__(512) void scan2_kernel(int* __restrict__ bsum) {
    int tid = threadIdx.x;
    int x = (tid < NSB) ? bsum[tid] : 0;
    int lane = tid & 63, wid = tid >> 6;
    int v = x;
    #pragma unroll
    for (int off = 1; off < 64; off <<= 1) {
        int t = __shfl_up(v, off, 64);
        if (lane >= off) v += t;
    }
    __shared__ int ws[8];
    if (lane == 63) ws[wid] = v;
    __syncthreads();
    int add = 0;
    for (int u = 0; u < wid; ++u) add += ws[u];
    v += add;
    if (tid < NSB) bsum[tid] = v - x;
}

__global__ __launch_bounds__(256) void scan3_kernel(
    const int* __restrict__ loc, const int* __restrict__ bsum,
    int* __restrict__ offs, int* __restrict__ cursor) {
    int i = blockIdx.x * 256 + threadIdx.x;
    if (i < KN) {
        int v = loc[i] + bsum[blockIdx.x];
        offs[i] = v;
        cursor[i] = v;
    }
    if (i == 0) offs[KN] = NEDGE;
}

// XCD-filtered scatter: block = (vb, xcd=blockIdx%8); processes edge slice
// [vb*EPV, (vb+1)*EPV) but ONLY edges with row/2500 == xcd. With round-robin
// block->XCD mapping, a bucket's cursor lines and cmeta region are written
// by one XCD only -> no cross-XCD ping-pong. Correct for ANY mapping.
__global__ __launch_bounds__(BLK) void scatter_kernel(
    const int* __restrict__ rows, const int* __restrict__ cols,
    const float* __restrict__ vals, int* __restrict__ cursor,
    unsigned int* __restrict__ cmeta) {
    int xcd = blockIdx.x & (NXCD - 1);
    int vb  = blockIdx.x >> 3;
    int ebase = vb * EPV;
    #pragma unroll
    for (int i = 0; i < EPV / BLK; ++i) {
        int e = ebase + i * BLK + threadIdx.x;
        int row = rows[e];
        if (row / (N_ / NXCD) != xcd) continue;
        int k = e / NNZ_;
        unsigned int b  = __float_as_uint(vals[e]);
        unsigned int rb = b + 0x1FFFu + ((b >> 14) & 1u);  // RNE to 9 mant
        int exp8 = (int)((rb >> 23) & 0xFF);
        unsigned int pk = 0u;
        if (exp8 > 96)                                     // else flush to 0
            pk = (b & 0x80000000u) | ((unsigned int)(exp8 - 96) << 26) |
                 (((rb >> 14) & 0x1FFu) << 17);
        pk |= ((unsigned int)k << 15) | (unsigned int)cols[e];
        int pos = atomicAdd(&cursor[row * K_ + k], 1);
        cmeta[pos] = pk;
    }
}

// ---------------- iteration kernels ----------------

// Accumulate edges [beg,end) into acc. bf16 gather (ushort4, 128B/row-read),
// fp32 FMA. Packed meta loaded lane-parallel per 64-edge chunk, decoded once
// per lane, broadcast via __shfl. Gathers batched (BATCH) for MLP.
// Pad column index = padc (in-bounds for the adjusted base).
template <int BATCH>
__device__ __forceinline__ void row_accum_bf(
    const unsigned int* __restrict__ cmeta, const ushort4* __restrict__ Xb,
    int beg, int end, int lane, int sub, int q, int padc, float4& acc) {
    for (int ebase = beg; ebase < end; ebase += 64) {
        int n = end - ebase;             // wave-uniform
        if (n > 64) n = 64;
        int   c_l = padc;
        float v_l = 0.0f;
        if (lane < n) {
            unsigned int p = cmeta[ebase + lane];
            c_l = (int)((p >> 15) & 3u) * N_ + (int)(p & 0x7FFFu);
            unsigned int e5 = (p >> 26) & 0x1Fu;
            unsigned int bits = (p & 0x80000000u) | ((e5 + 96u) << 23) |
                                (((p >> 17) & 0x1FFu) << 14);
            v_l = (e5 == 0u) ? 0.0f : __uint_as_float(bits);
        }
        int iters = (n + 3) >> 2;
        int itersPad = (iters + BATCH - 1) & ~(BATCH - 1);  // <= 16
        for (int it0 = 0; it0 < itersPad; it0 += BATCH) {
            float   vv[BATCH];
            ushort4 xx[BATCH];
            #pragma unroll
            for (int u = 0; u < BATCH; ++u) {
                int j = 4 * (it0 + u) + sub;      // < 64
                int   c = __shfl(c_l, j, 64);
                vv[u]   = __shfl(v_l, j, 64);
                xx[u]   = Xb[c * (FEAT_ / 4) + q];
            }
            #pragma unroll
            for (int u = 0; u < BATCH; ++u) {
                acc.x += vv[u] * bf2f(xx[u].x);
                acc.y += vv[u] * bf2f(xx[u].y);
                acc.z += vv[u] * bf2f(xx[u].z);
                acc.w += vv[u] * bf2f(xx[u].w);
            }
        }
    }
}

__device__ __forceinline__ void butterfly4(float4& a) {
    #pragma unroll
    for (int m = 16; m <= 32; m <<= 1) {
        a.x += __shfl_xor(a.x, m, 64);
        a.y += __shfl_xor(a.y, m, 64);
        a.z += __shfl_xor(a.z, m, 64);
        a.w += __shfl_xor(a.w, m, 64);
    }
}

// wave per R_SP contiguous CSR rows (rowid = n*K+k); acc = (W_k @ X)[n];
// fused v-update into bf16 V_bf (layout [k][n]). FIRST: Y=0, X=F_bf.
template <bool FIRST>
__global__ __launch_bounds__(BLK) void spmm_fused_kernel(
    const int* __restrict__ offs, const unsigned int* __restrict__ cmeta,
    const unsigned short* __restrict__ Xb,
    const float* __restrict__ d, unsigned short* __restrict__ V_bf) {
    int wave = (blockIdx.x * BLK + threadIdx.x) >> 6;
    int lane = threadIdx.x & 63;
    int sub  = lane >> 4, q = lane & 15;
    int base = wave * R_SP;
    if (base >= KN) return;
    int off_l = 0;
    if (lane <= R_SP) {
        int i = base + lane;
        if (i > KN) i = KN;
        off_l = offs[i];
    }
    const ushort4* X4 = (const ushort4*)Xb;
    ushort4* V4 = (ushort4*)V_bf;
    for (int r = 0; r < R_SP; ++r) {
        int w = base + r;                // rowid = n*K + k
        if (w >= KN) break;
        int k = w & (K_ - 1);
        int n = w >> 2;
        int beg = __shfl(off_l, r, 64);
        int end = __shfl(off_l, r + 1, 64);
        // decoded col' = k*N + col; recover shared-X indexing by base adjust
        const ushort4* X4m = X4 - (size_t)k * N_ * (FEAT_ / 4);
        float4 acc = {0.f, 0.f, 0.f, 0.f};
        row_accum_bf<4>(cmeta, X4m, beg, end, lane, sub, q, k * N_, acc);
        butterfly4(acc);                 // all lanes hold row sums
        if (sub == 0) {
            int idx4 = (k * N_ + n) * (FEAT_ / 4) + q;
            float thr = c_nu[k] * d[n];
            float4 y;
            if (FIRST) {
                y = make_float4(0.f, 0.f, 0.f, 0.f);
            } else {
                ushort4 vp = V4[idx4];   // v_{t-1}
                y.x = acc.x + bf2f(vp.x); y.y = acc.y + bf2f(vp.y);
                y.z = acc.z + bf2f(vp.z); y.w = acc.w + bf2f(vp.w);
            }
            ushort4 o;
            o.x = f2bf(y.x - softf(acc.x + y.x, thr));
            o.y = f2bf(y.y - softf(acc.y + y.y, thr));
            o.z = f2bf(y.z - softf(acc.z + y.z, thr));
            o.w = f2bf(y.w - softf(acc.w + y.w, thr));
            V4[idx4] = o;                // v_t
        }
    }
}

// wave per R_WT nodes: node n's edges over ALL k are one flat contiguous
// segment [offs[4n], offs[4n+4]) gathering V_bf[col'] directly.
// U = (dm*F - acc)/(dm+1), stored fp32 (d_out) + bf16 (gather copy).
__global__ __launch_bounds__(BLK) void wtv_u_kernel(
    const int* __restrict__ offs, const unsigned int* __restrict__ cmeta,
    const unsigned short* __restrict__ V_bf,
    const float* __restrict__ F, const float* __restrict__ dm,
    float* __restrict__ U, unsigned short* __restrict__ U_bf) {
    int wave = (blockIdx.x * BLK + threadIdx.x) >> 6;
    int lane = threadIdx.x & 63;
    int sub  = lane >> 4, q = lane & 15;
    int base = wave * R_WT;
    if (base >= N_) return;
    int off_l = 0;
    if (lane <= K_ * R_WT) {             // 17 offsets
        int i = K_ * base + lane;
        if (i > KN) i = KN;
        off_l = offs[i];
    }
    const ushort4* V4 = (const ushort4*)V_bf;
    for (int r = 0; r < R_WT; ++r) {
        int n = base + r;
        if (n >= N_) break;
        int beg = __shfl(off_l, K_ * r, 64);
        int end = __shfl(off_l, K_ * r + K_, 64);
        float4 acc = {0.f, 0.f, 0.f, 0.f};
        row_accum_bf<8>(cmeta, V4, beg, end, lane, sub, q, 0, acc);
        butterfly4(acc);
        if (sub == 0) {
            int idx4 = n * (FEAT_ / 4) + q;
            float dmv = dm[n];
            float r2 = 1.0f / (dmv + 1.0f);
            float4 f = ((const float4*)F)[idx4];
            float4 o;
            o.x = (dmv * f.x - acc.x) * r2; o.y = (dmv * f.y - acc.y) * r2;
            o.z = (dmv * f.z - acc.z) * r2; o.w = (dmv * f.w - acc.w) * r2;
            ((float4*)U)[idx4] = o;
            ushort4 ob;
            ob.x = f2bf(o.x); ob.y = f2bf(o.y);
            ob.z = f2bf(o.z); ob.w = f2bf(o.w);
            ((ushort4*)U_bf)[idx4] = ob;
        }
    }
}

extern "C" void kernel_launch(void* const* d_in, const int* in_sizes, int n_in,
                              void* d_out, int out_size, void* d_ws, size_t ws_size,
                              hipStream_t stream) {
    const float* F      = (const float*)d_in[0];
    const int*   w_rows = (const int*)d_in[1];
    const int*   w_cols = (const int*)d_in[2];
    const float* w_vals = (const float*)d_in[3];
    const float* d      = (const float*)d_in[4];
    const float* mask   = (const float*)d_in[5];
    float* U = (float*)d_out;

    // workspace layout (~29 MB)
    unsigned int* cmeta  = (unsigned int*)d_ws;               // NEDGE u32
    unsigned short* V_bf = (unsigned short*)(cmeta + NEDGE);  // KN*FEAT us
    unsigned short* U_bf = V_bf + (size_t)KN * FEAT_;         // NF us
    unsigned short* F_bf = U_bf + NF;                         // NF us
    float* dm     = (float*)(F_bf + NF);                      // N
    int*   cnt8   = (int*)(dm + N_);                          // NCPY*KN
    int*   loc    = cnt8 + NCPY * KN;                         // KN
    int*   bsum   = loc + KN;                                 // pad 512
    int*   offs   = bsum + 512;                               // KN+1
    int*   cursor = offs + KN + 1;                            // KN

    const int gEdge = NEDGE / BLK;                // 5000
    const int gNF4  = (NF / 4) / BLK;             // 1250

    // ---- CSR build + precompute ----
    hipMemsetAsync(cnt8, 0, (size_t)NCPY * KN * 4, stream);
    precompute_kernel<<<gNF4, BLK, 0, stream>>>(F, d, mask, dm, F_bf);
    hist_kernel<<<gEdge, BLK, 0, stream>>>(w_rows, cnt8);
    scan1_kernel<<<NSB, 256, 0, stream>>>(cnt8, loc, bsum);
    scan2_kernel<<<1, 512, 0, stream>>>(bsum);
    scan3_kernel<<<NSB, 256, 0, stream>>>(loc, bsum, offs, cursor);
    scatter_kernel<<<NVB * NXCD, BLK, 0, stream>>>(w_rows, w_cols, w_vals,
                                                   cursor, cmeta);

    // ---- iterations ----
    spmm_fused_kernel<true><<<NB_SP, BLK, 0, stream>>>(offs, cmeta, F_bf, d, V_bf);
    for (int it = 0; it < NITER; ++it) {
        wtv_u_kernel<<<NB_WT, BLK, 0, stream>>>(offs, cmeta, V_bf,
                                                F, dm, U, U_bf);
        if (it < NITER - 1)
            spmm_fused_kernel<false><<<NB_SP, BLK, 0, stream>>>(offs, cmeta,
                                                                U_bf, d, V_bf);
    }
}